// Round 5
// baseline (246.995 us; speedup 1.0000x reference)
//
#include <hip/hip_runtime.h>
#include <stdint.h>

// Problem constants
#define T_DIM 2048
#define B_DIM 4
#define D_DIM 1024
#define H_NUM 16
#define HD 64
#define MROWS (T_DIM * B_DIM)     // 8192 flattened (t*B+b) rows
#define QKV_N (3 * D_DIM)         // 3072
// softmax computed in log2 domain: scale = 1/sqrt(64) * log2(e)
#define ATT_C 0.18033688011112042f

typedef unsigned short u16;
typedef __bf16 bf16x8 __attribute__((ext_vector_type(8)));
typedef float f32x4 __attribute__((ext_vector_type(4)));
typedef float f32x16 __attribute__((ext_vector_type(16)));
typedef u16 u16x4 __attribute__((ext_vector_type(4)));
typedef u16 u16x8 __attribute__((ext_vector_type(8)));

__device__ __forceinline__ u16 f2bf(float f) {
  union { float f; unsigned u; } v; v.f = f;
  unsigned r = v.u + 0x7fffu + ((v.u >> 16) & 1u);
  return (u16)(r >> 16);
}

__device__ __forceinline__ void async_copy16(void* lds, const void* g) {
  __builtin_amdgcn_global_load_lds((__attribute__((address_space(1))) void*)(g),
                                   (__attribute__((address_space(3))) void*)(lds),
                                   16, 0, 0);
}

// ---------------- fp32 -> bf16 cast (memory-bound) ----------------
__global__ __launch_bounds__(256) void cast_f32_bf16(
    const float* __restrict__ src, u16* __restrict__ dst, int n4) {
  int i = blockIdx.x * 256 + threadIdx.x;
  if (i >= n4) return;
  float4 v = reinterpret_cast<const float4*>(src)[i];
  u16x4 o = {f2bf(v.x), f2bf(v.y), f2bf(v.z), f2bf(v.w)};
  reinterpret_cast<u16x4*>(dst)[i] = o;
}

// ---------------- bf16 GEMM: C[M][N] = A[M][K] * B[N][K]^T ----------------
// m97 structure + XCD-aware block swizzle (T1; nwg % 8 == 0 for all launches).
template <int OUT_F32_BIAS>
__global__ __launch_bounds__(256) void gemm_bt(
    const u16* __restrict__ A, const u16* __restrict__ Bm,
    u16* __restrict__ Cb, float* __restrict__ Cf, const float* __restrict__ bias,
    int M, int N, int K) {
  __shared__ __attribute__((aligned(16))) u16 As[128 * 64];
  __shared__ __attribute__((aligned(16))) u16 Bs[128 * 64];

  const int tid = threadIdx.x;
  const int lane = tid & 63, wid = tid >> 6;
  const int l15 = lane & 15, lg = lane >> 4;
  const int wr = wid >> 1, wc = wid & 1;

  // XCD swizzle: contiguous chunk of blocks per XCD (nwg divisible by 8)
  const int nwg = gridDim.x * gridDim.y;
  const int lin = blockIdx.y * gridDim.x + blockIdx.x;
  const int swz = (lin & 7) * (nwg >> 3) + (lin >> 3);
  const int bx = swz % gridDim.x, by = swz / gridDim.x;
  const int m0 = by * 128, n0 = bx * 128;

  f32x4 acc[4][4];
#pragma unroll
  for (int i = 0; i < 4; i++)
#pragma unroll
    for (int j = 0; j < 4; j++) acc[i][j] = (f32x4){0.f, 0.f, 0.f, 0.f};

  const int srow = tid >> 3;
  const int scol = (tid & 7) * 8;
  const u16* gA = A + (size_t)(m0 + srow) * K + scol;
  const u16* gB = Bm + (size_t)(n0 + srow) * K + scol;
  u16* lA = As + tid * 8;
  u16* lB = Bs + tid * 8;

  const int KT = K >> 6;
  for (int kt = 0; kt < KT; ++kt) {
    const int kofs = kt * 64;
#pragma unroll
    for (int p = 0; p < 4; ++p) {
      async_copy16(lA + p * 256 * 8, gA + (size_t)(p * 32) * K + kofs);
      async_copy16(lB + p * 256 * 8, gB + (size_t)(p * 32) * K + kofs);
    }
    __syncthreads();
#pragma unroll
    for (int kk = 0; kk < 2; ++kk) {
      bf16x8 af[4], bfr[4];
#pragma unroll
      for (int mt = 0; mt < 4; ++mt)
        af[mt] = *reinterpret_cast<const bf16x8*>(
            &As[(wr * 64 + mt * 16 + l15) * 64 + kk * 32 + lg * 8]);
#pragma unroll
      for (int nt = 0; nt < 4; ++nt)
        bfr[nt] = *reinterpret_cast<const bf16x8*>(
            &Bs[(wc * 64 + nt * 16 + l15) * 64 + kk * 32 + lg * 8]);
#pragma unroll
      for (int mt = 0; mt < 4; ++mt)
#pragma unroll
        for (int nt = 0; nt < 4; ++nt)
          acc[mt][nt] = __builtin_amdgcn_mfma_f32_16x16x32_bf16(
              af[mt], bfr[nt], acc[mt][nt], 0, 0, 0);
    }
    __syncthreads();
  }

#pragma unroll
  for (int mt = 0; mt < 4; ++mt) {
#pragma unroll
    for (int r = 0; r < 4; ++r) {
      const int row = m0 + wr * 64 + mt * 16 + lg * 4 + r;
#pragma unroll
      for (int nt = 0; nt < 4; ++nt) {
        const int col = n0 + wc * 64 + nt * 16 + l15;
        float v = acc[mt][nt][r];
        if (OUT_F32_BIAS) {
          Cf[(size_t)row * N + col] = v + bias[col];
        } else {
          Cb[(size_t)row * N + col] = f2bf(v);
        }
      }
    }
  }
}

// ---------------- causal flash attention, swapped-operand 32x32 ----------------
// Grid (16, B*H), XCD-swizzled. Block px owns one 128-row q-tile; 4 waves x
// 32 q-rows; iterations = 2*px+2 (scheduler backfills the imbalance at
// 4 blocks/CU). S^T = mfma(K,Q): lane owns q = lane&31 -> in-lane softmax
// (+1 shfl_xor(32)). Fast path skips causal mask when the whole tile is
// visible to the wave. exp2(fma(s, c, -m)) folds the scale. P repack via
// v_cvt_pk_bf16_f32 + v_permlane32_swap_b32; O^T = mfma(V^T, P).
__device__ __forceinline__ void process32(
    const bf16x8 (&qf)[4], f32x16 (&o)[2], float& m, float& l,
    int q0w, int kv0, int l31, int hi, bool needMask,
    const u16* __restrict__ Ks, const u16* __restrict__ Vf) {
  f32x16 s[2];
#pragma unroll
  for (int kb = 0; kb < 2; ++kb)
#pragma unroll
    for (int r = 0; r < 16; ++r) s[kb][r] = 0.f;

  // S^T[kv][q] = K . Q^T
  __builtin_amdgcn_s_setprio(1);
#pragma unroll
  for (int kb = 0; kb < 2; ++kb) {
#pragma unroll
    for (int ks = 0; ks < 4; ++ks) {
      const int row = kb * 32 + l31;
      bf16x8 kf = *reinterpret_cast<const bf16x8*>(
          &Ks[row * 64 + ((((ks << 1) | hi)) ^ (l31 & 7)) * 8]);
      s[kb] = __builtin_amdgcn_mfma_f32_32x32x16_bf16(kf, qf[ks], s[kb], 0, 0, 0);
    }
  }
  __builtin_amdgcn_s_setprio(0);

  // causal mask (slow path only) + in-lane max over RAW scores
  const int q = q0w + l31;
  float pmax = -1e30f;
  if (needMask) {
#pragma unroll
    for (int kb = 0; kb < 2; ++kb)
#pragma unroll
      for (int r = 0; r < 16; ++r) {
        const int kv = kv0 + kb * 32 + (r & 3) + ((r >> 2) << 3) + (hi << 2);
        if (kv > q) s[kb][r] = -1e30f;
        pmax = fmaxf(pmax, s[kb][r]);
      }
  } else {
#pragma unroll
    for (int kb = 0; kb < 2; ++kb)
#pragma unroll
      for (int r = 0; r < 16; ++r) pmax = fmaxf(pmax, s[kb][r]);
  }
  pmax *= ATT_C;
  pmax = fmaxf(pmax, __shfl_xor(pmax, 32, 64));

  // T13 defer-max online update
  if (!__all(pmax <= m + 8.0f)) {
    const float mnew = fmaxf(m, pmax);
    const float corr = __builtin_amdgcn_exp2f(m - mnew);
    m = mnew;
    l *= corr;
#pragma unroll
    for (int db = 0; db < 2; ++db)
#pragma unroll
      for (int r = 0; r < 16; ++r) o[db][r] *= corr;
  }
  float rsum = 0.f;
#pragma unroll
  for (int kb = 0; kb < 2; ++kb)
#pragma unroll
    for (int r = 0; r < 16; ++r) {
      float p = __builtin_amdgcn_exp2f(fmaf(s[kb][r], ATT_C, -m));
      s[kb][r] = p;
      rsum += p;
    }
  rsum += __shfl_xor(rsum, 32, 64);
  l += rsum;

  // repack P (f32, S^T layout) -> bf16 B-frags: 16 cvt_pk + 8 permlane32_swap
  union Frag { unsigned u[4]; bf16x8 v; };
  Frag pf[4];
#pragma unroll
  for (int kb = 0; kb < 2; ++kb)
#pragma unroll
    for (int g = 0; g < 2; ++g) {
#pragma unroll
      for (int t2 = 0; t2 < 2; ++t2) {
        unsigned x, y;
        asm("v_cvt_pk_bf16_f32 %0, %1, %2"
            : "=v"(x) : "v"(s[kb][g * 8 + t2 * 2]), "v"(s[kb][g * 8 + t2 * 2 + 1]));
        asm("v_cvt_pk_bf16_f32 %0, %1, %2"
            : "=v"(y) : "v"(s[kb][g * 8 + t2 * 2 + 4]), "v"(s[kb][g * 8 + t2 * 2 + 5]));
        asm("v_permlane32_swap_b32 %0, %1" : "+v"(x), "+v"(y));
        pf[kb * 2 + g].u[t2] = x;
        pf[kb * 2 + g].u[t2 + 2] = y;
      }
    }

  // O^T[d][q] += V^T . P
  __builtin_amdgcn_s_setprio(1);
#pragma unroll
  for (int ks = 0; ks < 4; ++ks) {
#pragma unroll
    for (int db = 0; db < 2; ++db) {
      bf16x8 vf = *reinterpret_cast<const bf16x8*>(
          &Vf[(ks * 2 + db) * 512 + l31 * 16 + hi * 8]);
      o[db] = __builtin_amdgcn_mfma_f32_32x32x16_bf16(vf, pf[ks].v, o[db], 0, 0, 0);
    }
  }
  __builtin_amdgcn_s_setprio(0);
}

__global__ __launch_bounds__(256, 4) void attn_kernel(
    const u16* __restrict__ qkv, u16* __restrict__ aout) {
  __shared__ __attribute__((aligned(16))) u16 Ks[64 * 64];  // swizzled rows
  __shared__ __attribute__((aligned(16))) u16 Vf[8 * 512];  // V^T frags

  const int tid = threadIdx.x;
  const int lane = tid & 63, w = tid >> 6;
  const int l31 = lane & 31, hi = lane >> 5;

  // XCD swizzle: 1024 blocks -> 128 contiguous per XCD (8 bh values, KV ~4MB)
  const int nwg = gridDim.x * gridDim.y;
  const int lin = blockIdx.y * gridDim.x + blockIdx.x;
  const int swz = (lin & 7) * (nwg >> 3) + (lin >> 3);
  const int px = swz % gridDim.x;           // q-tile 0..15
  const int bh = swz / gridDim.x;
  const int b = bh >> 4, h = bh & 15;
  const int q0w = px * 128 + w * 32;

  // Q fragments: lane(l31,hi) holds Q[q0w+l31][ks*16+hi*8+j]
  bf16x8 qf[4];
  {
    const u16* p = qkv + ((size_t)(q0w + l31) * B_DIM + b) * QKV_N + h * HD + hi * 8;
#pragma unroll
    for (int ks = 0; ks < 4; ++ks)
      qf[ks] = *reinterpret_cast<const bf16x8*>(p + ks * 16);
  }

  f32x16 o[2];
#pragma unroll
  for (int db = 0; db < 2; ++db)
#pragma unroll
    for (int r = 0; r < 16; ++r) o[db][r] = 0.f;
  float m = -1e30f, l = 0.f;

  const int srow = tid >> 3;                 // 0..31
  const int scol = (tid & 7) * 8;
  const int csw = (tid & 7) ^ (srow & 7);    // pre-swizzled K source chunk

  const int lastKt = 2 * px + 1;
  for (int kt = 0; kt <= lastKt; ++kt) {
    const int kv0 = kt * 64;
    // stage K tile (swizzled: linear LDS dest, inverse-swizzled source)
#pragma unroll
    for (int p = 0; p < 2; ++p) {
      const u16* gK = qkv + ((size_t)(kv0 + p * 32 + srow) * B_DIM + b) * QKV_N +
                      D_DIM + h * HD + csw * 8;
      async_copy16(Ks + tid * 8 + p * 2048, gK);
    }
    // stage V: global -> regs -> scatter into V^T fragment layout
    u16x8 vv[2];
#pragma unroll
    for (int p = 0; p < 2; ++p) {
      const u16* gV = qkv + ((size_t)(kv0 + p * 32 + srow) * B_DIM + b) * QKV_N +
                      2 * D_DIM + h * HD + scol;
      vv[p] = *reinterpret_cast<const u16x8*>(gV);
    }
#pragma unroll
    for (int p = 0; p < 2; ++p) {
      const int kvl = p * 32 + srow;         // 0..63
      const int fb = (kvl >> 4) * 2;
      const int e16 = kvl & 15;
#pragma unroll
      for (int j = 0; j < 8; ++j) {
        const int d = scol + j;
        Vf[(fb + (d >> 5)) * 512 + (d & 31) * 16 + e16] = vv[p][j];
      }
    }
    __syncthreads();

    if (kv0 <= q0w + 31) {
      const bool needMask = (kv0 + 63 > q0w);
      process32(qf, o, m, l, q0w, kv0, l31, hi, needMask, Ks, Vf);
    }
    __syncthreads();
  }

  // epilogue: O^T/l -> aout ; lane(l31,hi) holds O[q=l31][d=db*32+crow(r,hi)]
  {
    const float inv = 1.0f / l;
    u16* orow = aout + ((size_t)(q0w + l31) * B_DIM + b) * D_DIM + h * HD;
#pragma unroll
    for (int db = 0; db < 2; ++db)
#pragma unroll
      for (int rq = 0; rq < 4; ++rq) {
        u16x4 o4;
#pragma unroll
        for (int e = 0; e < 4; ++e) o4[e] = f2bf(o[db][rq * 4 + e] * inv);
        *reinterpret_cast<u16x4*>(orow + db * 32 + rq * 8 + hi * 4) = o4;
      }
  }
}

// ---------------- launch ----------------
extern "C" void kernel_launch(void* const* d_in, const int* in_sizes, int n_in,
                              void* d_out, int out_size, void* d_ws, size_t ws_size,
                              hipStream_t stream) {
  (void)in_sizes; (void)n_in; (void)out_size; (void)ws_size;
  const float* x = (const float*)d_in[0];
  const float* Wqkv = (const float*)d_in[1];
  const float* Wout = (const float*)d_in[2];
  const float* bout = (const float*)d_in[3];
  float* out = (float*)d_out;

  u16* xb = (u16*)d_ws;                               // [8192][1024]
  u16* wqkvb = xb + (size_t)MROWS * D_DIM;            // [3072][1024]
  u16* woutb = wqkvb + (size_t)QKV_N * D_DIM;         // [1024][1024]
  u16* qkv = woutb + (size_t)D_DIM * D_DIM;           // [8192][3072]
  u16* aout = qkv + (size_t)MROWS * QKV_N;            // [8192][1024]

  {
    int n4 = MROWS * D_DIM / 4;
    cast_f32_bf16<<<(n4 + 255) / 256, 256, 0, stream>>>(x, xb, n4);
  }
  {
    int n4 = QKV_N * D_DIM / 4;
    cast_f32_bf16<<<(n4 + 255) / 256, 256, 0, stream>>>(Wqkv, wqkvb, n4);
  }
  {
    int n4 = D_DIM * D_DIM / 4;
    cast_f32_bf16<<<(n4 + 255) / 256, 256, 0, stream>>>(Wout, woutb, n4);
  }

  gemm_bt<0><<<dim3(QKV_N / 128, MROWS / 128), 256, 0, stream>>>(
      xb, wqkvb, qkv, nullptr, nullptr, MROWS, QKV_N, D_DIM);

  attn_kernel<<<dim3(16, B_DIM * H_NUM), 256, 0, stream>>>(qkv, aout);

  gemm_bt<1><<<dim3(D_DIM / 128, MROWS / 128), 256, 0, stream>>>(
      aout, woutb, nullptr, out, bout, MROWS, D_DIM, D_DIM);
}

// Round 6
// 206.581 us; speedup vs baseline: 1.1956x; 1.1956x over previous
//
#include <hip/hip_runtime.h>
#include <stdint.h>

// Problem constants
#define T_DIM 2048
#define B_DIM 4
#define D_DIM 1024
#define H_NUM 16
#define HD 64
#define MROWS (T_DIM * B_DIM)     // 8192 flattened (t*B+b) rows
#define QKV_N (3 * D_DIM)         // 3072
// softmax computed in log2 domain: scale = 1/sqrt(64) * log2(e)
#define ATT_C 0.18033688011112042f

typedef unsigned short u16;
typedef __bf16 bf16x8 __attribute__((ext_vector_type(8)));
typedef float f32x4 __attribute__((ext_vector_type(4)));
typedef float f32x16 __attribute__((ext_vector_type(16)));
typedef u16 u16x4 __attribute__((ext_vector_type(4)));
typedef u16 u16x8 __attribute__((ext_vector_type(8)));

__device__ __forceinline__ u16 f2bf(float f) {
  union { float f; unsigned u; } v; v.f = f;
  unsigned r = v.u + 0x7fffu + ((v.u >> 16) & 1u);
  return (u16)(r >> 16);
}

__device__ __forceinline__ void async_copy16(void* lds, const void* g) {
  __builtin_amdgcn_global_load_lds((__attribute__((address_space(1))) void*)(g),
                                   (__attribute__((address_space(3))) void*)(lds),
                                   16, 0, 0);
}

// ---------------- fp32 -> bf16 cast (memory-bound) ----------------
__global__ __launch_bounds__(256) void cast_f32_bf16(
    const float* __restrict__ src, u16* __restrict__ dst, int n4) {
  int i = blockIdx.x * 256 + threadIdx.x;
  if (i >= n4) return;
  float4 v = reinterpret_cast<const float4*>(src)[i];
  u16x4 o = {f2bf(v.x), f2bf(v.y), f2bf(v.z), f2bf(v.w)};
  reinterpret_cast<u16x4*>(dst)[i] = o;
}

// ---------------- bf16 GEMM: C[M][N] = A[M][K] * B[N][K]^T ----------------
// m97 structure (no XCD swizzle — R4 showed it cost ~8us at these shapes).
template <int OUT_F32_BIAS>
__global__ __launch_bounds__(256) void gemm_bt(
    const u16* __restrict__ A, const u16* __restrict__ Bm,
    u16* __restrict__ Cb, float* __restrict__ Cf, const float* __restrict__ bias,
    int M, int N, int K) {
  __shared__ __attribute__((aligned(16))) u16 As[128 * 64];
  __shared__ __attribute__((aligned(16))) u16 Bs[128 * 64];

  const int tid = threadIdx.x;
  const int lane = tid & 63, wid = tid >> 6;
  const int l15 = lane & 15, lg = lane >> 4;
  const int wr = wid >> 1, wc = wid & 1;
  const int m0 = blockIdx.y * 128, n0 = blockIdx.x * 128;

  f32x4 acc[4][4];
#pragma unroll
  for (int i = 0; i < 4; i++)
#pragma unroll
    for (int j = 0; j < 4; j++) acc[i][j] = (f32x4){0.f, 0.f, 0.f, 0.f};

  const int srow = tid >> 3;
  const int scol = (tid & 7) * 8;
  const u16* gA = A + (size_t)(m0 + srow) * K + scol;
  const u16* gB = Bm + (size_t)(n0 + srow) * K + scol;
  u16* lA = As + tid * 8;
  u16* lB = Bs + tid * 8;

  const int KT = K >> 6;
  for (int kt = 0; kt < KT; ++kt) {
    const int kofs = kt * 64;
#pragma unroll
    for (int p = 0; p < 4; ++p) {
      async_copy16(lA + p * 256 * 8, gA + (size_t)(p * 32) * K + kofs);
      async_copy16(lB + p * 256 * 8, gB + (size_t)(p * 32) * K + kofs);
    }
    __syncthreads();
#pragma unroll
    for (int kk = 0; kk < 2; ++kk) {
      bf16x8 af[4], bfr[4];
#pragma unroll
      for (int mt = 0; mt < 4; ++mt)
        af[mt] = *reinterpret_cast<const bf16x8*>(
            &As[(wr * 64 + mt * 16 + l15) * 64 + kk * 32 + lg * 8]);
#pragma unroll
      for (int nt = 0; nt < 4; ++nt)
        bfr[nt] = *reinterpret_cast<const bf16x8*>(
            &Bs[(wc * 64 + nt * 16 + l15) * 64 + kk * 32 + lg * 8]);
#pragma unroll
      for (int mt = 0; mt < 4; ++mt)
#pragma unroll
        for (int nt = 0; nt < 4; ++nt)
          acc[mt][nt] = __builtin_amdgcn_mfma_f32_16x16x32_bf16(
              af[mt], bfr[nt], acc[mt][nt], 0, 0, 0);
    }
    __syncthreads();
  }

#pragma unroll
  for (int mt = 0; mt < 4; ++mt) {
#pragma unroll
    for (int r = 0; r < 4; ++r) {
      const int row = m0 + wr * 64 + mt * 16 + lg * 4 + r;
#pragma unroll
      for (int nt = 0; nt < 4; ++nt) {
        const int col = n0 + wc * 64 + nt * 16 + l15;
        float v = acc[mt][nt][r];
        if (OUT_F32_BIAS) {
          Cf[(size_t)row * N + col] = v + bias[col];
        } else {
          Cb[(size_t)row * N + col] = f2bf(v);
        }
      }
    }
  }
}

// ---------------- causal flash attention, swapped-operand 32x32 ----------------
// Grid (8, B*H), XCD-swizzled, paired q-tiles qtA=px / qtB=15-px (128 rows
// each) -> uniform per-block work, A/B processed sequentially per kv tile
// (single live S-state, no spills). S^T = mfma(K,Q): lane owns q = lane&31 ->
// in-lane softmax (+1 shfl_xor(32)). Fast path skips the causal mask when the
// tile is fully visible; exp2(fma(s,c,-m)) folds the scale. P repack via
// v_cvt_pk_bf16_f32 + v_permlane32_swap_b32. O^T = mfma(V^T, P).
// V frags padded to 24 u16/row (read granules spread over all 32 banks) and
// the scatter rotates its inner index by srow to break write conflicts.
#define VF_STRIDE 24
#define VF_FRAG (32 * VF_STRIDE)

__device__ __forceinline__ void process32(
    const bf16x8 (&qf)[4], f32x16 (&o)[2], float& m, float& l,
    int q0w, int kv0, int l31, int hi, bool needMask,
    const u16* __restrict__ Ks, const u16* __restrict__ Vf) {
  f32x16 s[2];
#pragma unroll
  for (int kb = 0; kb < 2; ++kb)
#pragma unroll
    for (int r = 0; r < 16; ++r) s[kb][r] = 0.f;

  // S^T[kv][q] = K . Q^T
  __builtin_amdgcn_s_setprio(1);
#pragma unroll
  for (int kb = 0; kb < 2; ++kb) {
#pragma unroll
    for (int ks = 0; ks < 4; ++ks) {
      const int row = kb * 32 + l31;
      bf16x8 kf = *reinterpret_cast<const bf16x8*>(
          &Ks[row * 64 + ((((ks << 1) | hi)) ^ (l31 & 7)) * 8]);
      s[kb] = __builtin_amdgcn_mfma_f32_32x32x16_bf16(kf, qf[ks], s[kb], 0, 0, 0);
    }
  }
  __builtin_amdgcn_s_setprio(0);

  // causal mask (slow path only) + in-lane max over RAW scores
  const int q = q0w + l31;
  float pmax = -1e30f;
  if (needMask) {
#pragma unroll
    for (int kb = 0; kb < 2; ++kb)
#pragma unroll
      for (int r = 0; r < 16; ++r) {
        const int kv = kv0 + kb * 32 + (r & 3) + ((r >> 2) << 3) + (hi << 2);
        if (kv > q) s[kb][r] = -1e30f;
        pmax = fmaxf(pmax, s[kb][r]);
      }
  } else {
#pragma unroll
    for (int kb = 0; kb < 2; ++kb)
#pragma unroll
      for (int r = 0; r < 16; ++r) pmax = fmaxf(pmax, s[kb][r]);
  }
  pmax *= ATT_C;
  pmax = fmaxf(pmax, __shfl_xor(pmax, 32, 64));

  // T13 defer-max online update
  if (!__all(pmax <= m + 8.0f)) {
    const float mnew = fmaxf(m, pmax);
    const float corr = __builtin_amdgcn_exp2f(m - mnew);
    m = mnew;
    l *= corr;
#pragma unroll
    for (int db = 0; db < 2; ++db)
#pragma unroll
      for (int r = 0; r < 16; ++r) o[db][r] *= corr;
  }
  float rsum = 0.f;
#pragma unroll
  for (int kb = 0; kb < 2; ++kb)
#pragma unroll
    for (int r = 0; r < 16; ++r) {
      float p = __builtin_amdgcn_exp2f(fmaf(s[kb][r], ATT_C, -m));
      s[kb][r] = p;
      rsum += p;
    }
  rsum += __shfl_xor(rsum, 32, 64);
  l += rsum;

  // repack P (f32, S^T layout) -> bf16 B-frags: 16 cvt_pk + 8 permlane32_swap
  union Frag { unsigned u[4]; bf16x8 v; };
  Frag pf[4];
#pragma unroll
  for (int kb = 0; kb < 2; ++kb)
#pragma unroll
    for (int g = 0; g < 2; ++g) {
#pragma unroll
      for (int t2 = 0; t2 < 2; ++t2) {
        unsigned x, y;
        asm("v_cvt_pk_bf16_f32 %0, %1, %2"
            : "=v"(x) : "v"(s[kb][g * 8 + t2 * 2]), "v"(s[kb][g * 8 + t2 * 2 + 1]));
        asm("v_cvt_pk_bf16_f32 %0, %1, %2"
            : "=v"(y) : "v"(s[kb][g * 8 + t2 * 2 + 4]), "v"(s[kb][g * 8 + t2 * 2 + 5]));
        asm("v_permlane32_swap_b32 %0, %1" : "+v"(x), "+v"(y));
        pf[kb * 2 + g].u[t2] = x;
        pf[kb * 2 + g].u[t2 + 2] = y;
      }
    }

  // O^T[d][q] += V^T . P
  __builtin_amdgcn_s_setprio(1);
#pragma unroll
  for (int ks = 0; ks < 4; ++ks) {
#pragma unroll
    for (int db = 0; db < 2; ++db) {
      bf16x8 vf = *reinterpret_cast<const bf16x8*>(
          &Vf[(ks * 2 + db) * VF_FRAG + l31 * VF_STRIDE + hi * 8]);
      o[db] = __builtin_amdgcn_mfma_f32_32x32x16_bf16(vf, pf[ks].v, o[db], 0, 0, 0);
    }
  }
  __builtin_amdgcn_s_setprio(0);
}

__global__ __launch_bounds__(256, 2) void attn_kernel(
    const u16* __restrict__ qkv, u16* __restrict__ aout) {
  __shared__ __attribute__((aligned(16))) u16 Ks[64 * 64];       // swizzled rows
  __shared__ __attribute__((aligned(16))) u16 Vf[8 * VF_FRAG];   // V^T frags, padded

  const int tid = threadIdx.x;
  const int lane = tid & 63, w = tid >> 6;
  const int l31 = lane & 31, hi = lane >> 5;

  // XCD swizzle: 512 blocks -> 64 contiguous per XCD (KV reuse in XCD L2)
  const int nwg = gridDim.x * gridDim.y;          // 512
  const int lin = blockIdx.y * gridDim.x + blockIdx.x;
  const int swz = (lin & 7) * (nwg >> 3) + (lin >> 3);
  const int px = swz % gridDim.x;                 // pair index 0..7
  const int bh = swz / gridDim.x;
  const int b = bh >> 4, h = bh & 15;
  const int qtA = px, qtB = 15 - px;              // qtA < qtB
  const int q0A = qtA * 128 + w * 32, q0B = qtB * 128 + w * 32;

  // Q fragments: lane(l31,hi) holds Q[q0+l31][ks*16+hi*8+j]
  bf16x8 qfA[4], qfB[4];
  {
    const u16* pA = qkv + ((size_t)(q0A + l31) * B_DIM + b) * QKV_N + h * HD + hi * 8;
    const u16* pB = qkv + ((size_t)(q0B + l31) * B_DIM + b) * QKV_N + h * HD + hi * 8;
#pragma unroll
    for (int ks = 0; ks < 4; ++ks) {
      qfA[ks] = *reinterpret_cast<const bf16x8*>(pA + ks * 16);
      qfB[ks] = *reinterpret_cast<const bf16x8*>(pB + ks * 16);
    }
  }

  f32x16 oA[2], oB[2];
#pragma unroll
  for (int db = 0; db < 2; ++db)
#pragma unroll
    for (int r = 0; r < 16; ++r) { oA[db][r] = 0.f; oB[db][r] = 0.f; }
  float mA = -1e30f, lA = 0.f, mB = -1e30f, lB = 0.f;

  const int srow = tid >> 3;                 // 0..31
  const int scol = (tid & 7) * 8;
  const int csw = (tid & 7) ^ (srow & 7);    // pre-swizzled K source chunk

  const int lastKt = 2 * qtB + 1;
  for (int kt = 0; kt <= lastKt; ++kt) {
    const int kv0 = kt * 64;
    // stage K tile (swizzled: linear LDS dest, inverse-swizzled source)
#pragma unroll
    for (int p = 0; p < 2; ++p) {
      const u16* gK = qkv + ((size_t)(kv0 + p * 32 + srow) * B_DIM + b) * QKV_N +
                      D_DIM + h * HD + csw * 8;
      async_copy16(Ks + tid * 8 + p * 2048, gK);
    }
    // stage V: global -> regs -> scatter into padded V^T fragment layout
    u16x8 vv[2];
#pragma unroll
    for (int p = 0; p < 2; ++p) {
      const u16* gV = qkv + ((size_t)(kv0 + p * 32 + srow) * B_DIM + b) * QKV_N +
                      2 * D_DIM + h * HD + scol;
      vv[p] = *reinterpret_cast<const u16x8*>(gV);
    }
#pragma unroll
    for (int p = 0; p < 2; ++p) {
      const int kvl = p * 32 + srow;         // 0..63
      const int fb = (kvl >> 4) * 2;
      const int e16 = kvl & 15;
#pragma unroll
      for (int jj = 0; jj < 8; ++jj) {
        const int j = (jj + srow) & 7;       // rotate: concurrent writes span rows
        const int d = scol + j;
        Vf[(fb + (d >> 5)) * VF_FRAG + (d & 31) * VF_STRIDE + e16] = vv[p][j];
      }
    }
    __syncthreads();

    if (kv0 <= q0A + 31) {
      const bool needMask = (kv0 + 63 > q0A);
      process32(qfA, oA, mA, lA, q0A, kv0, l31, hi, needMask, Ks, Vf);
    }
    if (kv0 <= q0B + 31) {
      const bool needMask = (kv0 + 63 > q0B);
      process32(qfB, oB, mB, lB, q0B, kv0, l31, hi, needMask, Ks, Vf);
    }
    __syncthreads();
  }

  // epilogue: O^T/l -> aout ; lane(l31,hi) holds O[q=l31][d=db*32+8*rq+4*hi+e]
#pragma unroll
  for (int t = 0; t < 2; ++t) {
    const float inv = t == 0 ? (1.0f / lA) : (1.0f / lB);
    const int q0w = t == 0 ? q0A : q0B;
    f32x16* o = t == 0 ? oA : oB;
    u16* orow = aout + ((size_t)(q0w + l31) * B_DIM + b) * D_DIM + h * HD;
#pragma unroll
    for (int db = 0; db < 2; ++db)
#pragma unroll
      for (int rq = 0; rq < 4; ++rq) {
        u16x4 o4;
#pragma unroll
        for (int e = 0; e < 4; ++e) o4[e] = f2bf(o[db][rq * 4 + e] * inv);
        *reinterpret_cast<u16x4*>(orow + db * 32 + rq * 8 + hi * 4) = o4;
      }
  }
}

// ---------------- launch ----------------
extern "C" void kernel_launch(void* const* d_in, const int* in_sizes, int n_in,
                              void* d_out, int out_size, void* d_ws, size_t ws_size,
                              hipStream_t stream) {
  (void)in_sizes; (void)n_in; (void)out_size; (void)ws_size;
  const float* x = (const float*)d_in[0];
  const float* Wqkv = (const float*)d_in[1];
  const float* Wout = (const float*)d_in[2];
  const float* bout = (const float*)d_in[3];
  float* out = (float*)d_out;

  u16* xb = (u16*)d_ws;                               // [8192][1024]
  u16* wqkvb = xb + (size_t)MROWS * D_DIM;            // [3072][1024]
  u16* woutb = wqkvb + (size_t)QKV_N * D_DIM;         // [1024][1024]
  u16* qkv = woutb + (size_t)D_DIM * D_DIM;           // [8192][3072]
  u16* aout = qkv + (size_t)MROWS * QKV_N;            // [8192][1024]

  {
    int n4 = MROWS * D_DIM / 4;
    cast_f32_bf16<<<(n4 + 255) / 256, 256, 0, stream>>>(x, xb, n4);
  }
  {
    int n4 = QKV_N * D_DIM / 4;
    cast_f32_bf16<<<(n4 + 255) / 256, 256, 0, stream>>>(Wqkv, wqkvb, n4);
  }
  {
    int n4 = D_DIM * D_DIM / 4;
    cast_f32_bf16<<<(n4 + 255) / 256, 256, 0, stream>>>(Wout, woutb, n4);
  }

  gemm_bt<0><<<dim3(QKV_N / 128, MROWS / 128), 256, 0, stream>>>(
      xb, wqkvb, qkv, nullptr, nullptr, MROWS, QKV_N, D_DIM);

  attn_kernel<<<dim3(8, B_DIM * H_NUM), 256, 0, stream>>>(qkv, aout);

  gemm_bt<1><<<dim3(D_DIM / 128, MROWS / 128), 256, 0, stream>>>(
      aout, woutb, nullptr, out, bout, MROWS, D_DIM, D_DIM);
}

// Round 7
// 204.996 us; speedup vs baseline: 1.2049x; 1.0077x over previous
//
#include <hip/hip_runtime.h>
#include <stdint.h>

// Problem constants
#define T_DIM 2048
#define B_DIM 4
#define D_DIM 1024
#define H_NUM 16
#define HD 64
#define MROWS (T_DIM * B_DIM)     // 8192 flattened (t*B+b) rows
#define QKV_N (3 * D_DIM)         // 3072
// softmax computed in log2 domain: scale = 1/sqrt(64) * log2(e)
#define ATT_C 0.18033688011112042f

typedef unsigned short u16;
typedef __bf16 bf16x8 __attribute__((ext_vector_type(8)));
typedef float f32x4 __attribute__((ext_vector_type(4)));
typedef float f32x16 __attribute__((ext_vector_type(16)));
typedef u16 u16x4 __attribute__((ext_vector_type(4)));
typedef u16 u16x8 __attribute__((ext_vector_type(8)));

__device__ __forceinline__ u16 f2bf(float f) {
  union { float f; unsigned u; } v; v.f = f;
  unsigned r = v.u + 0x7fffu + ((v.u >> 16) & 1u);
  return (u16)(r >> 16);
}

__device__ __forceinline__ void async_copy16(void* lds, const void* g) {
  __builtin_amdgcn_global_load_lds((__attribute__((address_space(1))) void*)(g),
                                   (__attribute__((address_space(3))) void*)(lds),
                                   16, 0, 0);
}

// ---------------- fused fp32 -> bf16 cast (3 inputs, contiguous dst) -------
__global__ __launch_bounds__(256) void cast3_f32_bf16(
    const float* __restrict__ s0, const float* __restrict__ s1,
    const float* __restrict__ s2, u16* __restrict__ dst,
    int n0, int n01, int ntot4) {
  int i = blockIdx.x * 256 + threadIdx.x;
  if (i >= ntot4) return;
  int e = i * 4;
  const float* s; int off;
  if (e < n0) { s = s0; off = 0; }
  else if (e < n01) { s = s1; off = n0; }
  else { s = s2; off = n01; }
  float4 v = *reinterpret_cast<const float4*>(s + (e - off));
  u16x4 o = {f2bf(v.x), f2bf(v.y), f2bf(v.z), f2bf(v.w)};
  *reinterpret_cast<u16x4*>(dst + e) = o;
}

// ---------------- bf16 GEMM: C[M][N] = A[M][K] * B[N][K]^T ----------------
// m97 structure (unchanged).
template <int OUT_F32_BIAS>
__global__ __launch_bounds__(256) void gemm_bt(
    const u16* __restrict__ A, const u16* __restrict__ Bm,
    u16* __restrict__ Cb, float* __restrict__ Cf, const float* __restrict__ bias,
    int M, int N, int K) {
  __shared__ __attribute__((aligned(16))) u16 As[128 * 64];
  __shared__ __attribute__((aligned(16))) u16 Bs[128 * 64];

  const int tid = threadIdx.x;
  const int lane = tid & 63, wid = tid >> 6;
  const int l15 = lane & 15, lg = lane >> 4;
  const int wr = wid >> 1, wc = wid & 1;
  const int m0 = blockIdx.y * 128, n0 = blockIdx.x * 128;

  f32x4 acc[4][4];
#pragma unroll
  for (int i = 0; i < 4; i++)
#pragma unroll
    for (int j = 0; j < 4; j++) acc[i][j] = (f32x4){0.f, 0.f, 0.f, 0.f};

  const int srow = tid >> 3;
  const int scol = (tid & 7) * 8;
  const u16* gA = A + (size_t)(m0 + srow) * K + scol;
  const u16* gB = Bm + (size_t)(n0 + srow) * K + scol;
  u16* lA = As + tid * 8;
  u16* lB = Bs + tid * 8;

  const int KT = K >> 6;
  for (int kt = 0; kt < KT; ++kt) {
    const int kofs = kt * 64;
#pragma unroll
    for (int p = 0; p < 4; ++p) {
      async_copy16(lA + p * 256 * 8, gA + (size_t)(p * 32) * K + kofs);
      async_copy16(lB + p * 256 * 8, gB + (size_t)(p * 32) * K + kofs);
    }
    __syncthreads();
#pragma unroll
    for (int kk = 0; kk < 2; ++kk) {
      bf16x8 af[4], bfr[4];
#pragma unroll
      for (int mt = 0; mt < 4; ++mt)
        af[mt] = *reinterpret_cast<const bf16x8*>(
            &As[(wr * 64 + mt * 16 + l15) * 64 + kk * 32 + lg * 8]);
#pragma unroll
      for (int nt = 0; nt < 4; ++nt)
        bfr[nt] = *reinterpret_cast<const bf16x8*>(
            &Bs[(wc * 64 + nt * 16 + l15) * 64 + kk * 32 + lg * 8]);
#pragma unroll
      for (int mt = 0; mt < 4; ++mt)
#pragma unroll
        for (int nt = 0; nt < 4; ++nt)
          acc[mt][nt] = __builtin_amdgcn_mfma_f32_16x16x32_bf16(
              af[mt], bfr[nt], acc[mt][nt], 0, 0, 0);
    }
    __syncthreads();
  }

#pragma unroll
  for (int mt = 0; mt < 4; ++mt) {
#pragma unroll
    for (int r = 0; r < 4; ++r) {
      const int row = m0 + wr * 64 + mt * 16 + lg * 4 + r;
#pragma unroll
      for (int nt = 0; nt < 4; ++nt) {
        const int col = n0 + wc * 64 + nt * 16 + l15;
        float v = acc[mt][nt][r];
        if (OUT_F32_BIAS) {
          Cf[(size_t)row * N + col] = v + bias[col];
        } else {
          Cb[(size_t)row * N + col] = f2bf(v);
        }
      }
    }
  }
}

// ---------------- causal flash attention, swapped-operand 32x32 ----------------
// R5 structure + DOUBLE-BUFFERED K/V staging: issue tile t+1's K global_load_lds
// and V global loads before processing tile t; scatter V(t+1) after compute
// (per-wave vmcnt covers the regs); ONE barrier per tile (prev barrier already
// separates buf^1 readers from new writes).
#define VF_STRIDE 24
#define VF_FRAG (32 * VF_STRIDE)

__device__ __forceinline__ void process32(
    const bf16x8 (&qf)[4], f32x16 (&o)[2], float& m, float& l,
    int q0w, int kv0, int l31, int hi, bool needMask,
    const u16* __restrict__ Ks, const u16* __restrict__ Vf) {
  f32x16 s[2];
#pragma unroll
  for (int kb = 0; kb < 2; ++kb)
#pragma unroll
    for (int r = 0; r < 16; ++r) s[kb][r] = 0.f;

  // S^T[kv][q] = K . Q^T
  __builtin_amdgcn_s_setprio(1);
#pragma unroll
  for (int kb = 0; kb < 2; ++kb) {
#pragma unroll
    for (int ks = 0; ks < 4; ++ks) {
      const int row = kb * 32 + l31;
      bf16x8 kf = *reinterpret_cast<const bf16x8*>(
          &Ks[row * 64 + ((((ks << 1) | hi)) ^ (l31 & 7)) * 8]);
      s[kb] = __builtin_amdgcn_mfma_f32_32x32x16_bf16(kf, qf[ks], s[kb], 0, 0, 0);
    }
  }
  __builtin_amdgcn_s_setprio(0);

  // causal mask (slow path only) + in-lane max over RAW scores
  const int q = q0w + l31;
  float pmax = -1e30f;
  if (needMask) {
#pragma unroll
    for (int kb = 0; kb < 2; ++kb)
#pragma unroll
      for (int r = 0; r < 16; ++r) {
        const int kv = kv0 + kb * 32 + (r & 3) + ((r >> 2) << 3) + (hi << 2);
        if (kv > q) s[kb][r] = -1e30f;
        pmax = fmaxf(pmax, s[kb][r]);
      }
  } else {
#pragma unroll
    for (int kb = 0; kb < 2; ++kb)
#pragma unroll
      for (int r = 0; r < 16; ++r) pmax = fmaxf(pmax, s[kb][r]);
  }
  pmax *= ATT_C;
  pmax = fmaxf(pmax, __shfl_xor(pmax, 32, 64));

  // T13 defer-max online update
  if (!__all(pmax <= m + 8.0f)) {
    const float mnew = fmaxf(m, pmax);
    const float corr = __builtin_amdgcn_exp2f(m - mnew);
    m = mnew;
    l *= corr;
#pragma unroll
    for (int db = 0; db < 2; ++db)
#pragma unroll
      for (int r = 0; r < 16; ++r) o[db][r] *= corr;
  }
  float rsum = 0.f;
#pragma unroll
  for (int kb = 0; kb < 2; ++kb)
#pragma unroll
    for (int r = 0; r < 16; ++r) {
      float p = __builtin_amdgcn_exp2f(fmaf(s[kb][r], ATT_C, -m));
      s[kb][r] = p;
      rsum += p;
    }
  rsum += __shfl_xor(rsum, 32, 64);
  l += rsum;

  // repack P (f32, S^T layout) -> bf16 B-frags: 16 cvt_pk + 8 permlane32_swap
  union Frag { unsigned u[4]; bf16x8 v; };
  Frag pf[4];
#pragma unroll
  for (int kb = 0; kb < 2; ++kb)
#pragma unroll
    for (int g = 0; g < 2; ++g) {
#pragma unroll
      for (int t2 = 0; t2 < 2; ++t2) {
        unsigned x, y;
        asm("v_cvt_pk_bf16_f32 %0, %1, %2"
            : "=v"(x) : "v"(s[kb][g * 8 + t2 * 2]), "v"(s[kb][g * 8 + t2 * 2 + 1]));
        asm("v_cvt_pk_bf16_f32 %0, %1, %2"
            : "=v"(y) : "v"(s[kb][g * 8 + t2 * 2 + 4]), "v"(s[kb][g * 8 + t2 * 2 + 5]));
        asm("v_permlane32_swap_b32 %0, %1" : "+v"(x), "+v"(y));
        pf[kb * 2 + g].u[t2] = x;
        pf[kb * 2 + g].u[t2 + 2] = y;
      }
    }

  // O^T[d][q] += V^T . P
  __builtin_amdgcn_s_setprio(1);
#pragma unroll
  for (int ks = 0; ks < 4; ++ks) {
#pragma unroll
    for (int db = 0; db < 2; ++db) {
      bf16x8 vf = *reinterpret_cast<const bf16x8*>(
          &Vf[(ks * 2 + db) * VF_FRAG + l31 * VF_STRIDE + hi * 8]);
      o[db] = __builtin_amdgcn_mfma_f32_32x32x16_bf16(vf, pf[ks].v, o[db], 0, 0, 0);
    }
  }
  __builtin_amdgcn_s_setprio(0);
}

__global__ __launch_bounds__(256, 2) void attn_kernel(
    const u16* __restrict__ qkv, u16* __restrict__ aout) {
  __shared__ __attribute__((aligned(16))) u16 Ks[2][64 * 64];      // swizzled
  __shared__ __attribute__((aligned(16))) u16 Vf[2][8 * VF_FRAG];  // padded frags

  const int tid = threadIdx.x;
  const int lane = tid & 63, w = tid >> 6;
  const int l31 = lane & 31, hi = lane >> 5;

  // XCD swizzle: 512 blocks -> 64 contiguous per XCD (KV reuse in XCD L2)
  const int nwg = gridDim.x * gridDim.y;          // 512
  const int lin = blockIdx.y * gridDim.x + blockIdx.x;
  const int swz = (lin & 7) * (nwg >> 3) + (lin >> 3);
  const int px = swz % gridDim.x;                 // pair index 0..7
  const int bh = swz / gridDim.x;
  const int b = bh >> 4, h = bh & 15;
  const int qtA = px, qtB = 15 - px;              // qtA < qtB
  const int q0A = qtA * 128 + w * 32, q0B = qtB * 128 + w * 32;

  // Q fragments: lane(l31,hi) holds Q[q0+l31][ks*16+hi*8+j]
  bf16x8 qfA[4], qfB[4];
  {
    const u16* pA = qkv + ((size_t)(q0A + l31) * B_DIM + b) * QKV_N + h * HD + hi * 8;
    const u16* pB = qkv + ((size_t)(q0B + l31) * B_DIM + b) * QKV_N + h * HD + hi * 8;
#pragma unroll
    for (int ks = 0; ks < 4; ++ks) {
      qfA[ks] = *reinterpret_cast<const bf16x8*>(pA + ks * 16);
      qfB[ks] = *reinterpret_cast<const bf16x8*>(pB + ks * 16);
    }
  }

  f32x16 oA[2], oB[2];
#pragma unroll
  for (int db = 0; db < 2; ++db)
#pragma unroll
    for (int r = 0; r < 16; ++r) { oA[db][r] = 0.f; oB[db][r] = 0.f; }
  float mA = -1e30f, lA = 0.f, mB = -1e30f, lB = 0.f;

  const int srow = tid >> 3;                 // 0..31
  const int scol = (tid & 7) * 8;
  const int csw = (tid & 7) ^ (srow & 7);    // pre-swizzled K source chunk

  // staging helpers -----------------------------------------------------
  const int kvl0 = srow, kvl1 = 32 + srow;
  const int fb0 = (kvl0 >> 4) * 2, e0 = kvl0 & 15;
  const int fb1 = (kvl1 >> 4) * 2, e1 = kvl1 & 15;

#define ISSUE_K(kt_, buf_)                                                       \
  {                                                                              \
    const int kv0_ = (kt_) * 64;                                                 \
    _Pragma("unroll") for (int p = 0; p < 2; ++p) {                              \
      const u16* gK = qkv + ((size_t)(kv0_ + p * 32 + srow) * B_DIM + b) * QKV_N \
                      + D_DIM + h * HD + csw * 8;                                \
      async_copy16(&Ks[buf_][tid * 8 + p * 2048], gK);                           \
    }                                                                            \
  }

#define LOAD_V(kt_, vv_)                                                         \
  {                                                                              \
    const int kv0_ = (kt_) * 64;                                                 \
    _Pragma("unroll") for (int p = 0; p < 2; ++p) {                              \
      const u16* gV = qkv + ((size_t)(kv0_ + p * 32 + srow) * B_DIM + b) * QKV_N \
                      + 2 * D_DIM + h * HD + scol;                               \
      vv_[p] = *reinterpret_cast<const u16x8*>(gV);                              \
    }                                                                            \
  }

#define SCATTER_V(vv_, buf_)                                                     \
  {                                                                              \
    _Pragma("unroll") for (int jj = 0; jj < 8; ++jj) {                           \
      const int j = (jj + srow) & 7;                                             \
      const int d = scol + j;                                                    \
      Vf[buf_][(fb0 + (d >> 5)) * VF_FRAG + (d & 31) * VF_STRIDE + e0] = vv_[0][j]; \
      Vf[buf_][(fb1 + (d >> 5)) * VF_FRAG + (d & 31) * VF_STRIDE + e1] = vv_[1][j]; \
    }                                                                            \
  }

  const int lastKt = 2 * qtB + 1;
  // prologue: stage tile 0 into buffer 0
  {
    u16x8 vv[2];
    ISSUE_K(0, 0);
    LOAD_V(0, vv);
    SCATTER_V(vv, 0);
  }
  __syncthreads();

  for (int kt = 0; kt <= lastKt; ++kt) {
    const int cur = kt & 1;
    const int kv0 = kt * 64;
    u16x8 vvn[2];
    const bool pre = (kt < lastKt);
    if (pre) {
      ISSUE_K(kt + 1, cur ^ 1);
      LOAD_V(kt + 1, vvn);
    }

    if (kv0 <= q0A + 31) {
      const bool needMask = (kv0 + 63 > q0A);
      process32(qfA, oA, mA, lA, q0A, kv0, l31, hi, needMask, Ks[cur], Vf[cur]);
    }
    {
      const bool needMask = (kv0 + 63 > q0B);
      process32(qfB, oB, mB, lB, q0B, kv0, l31, hi, needMask, Ks[cur], Vf[cur]);
    }

    if (pre) SCATTER_V(vvn, cur ^ 1);
    __syncthreads();
  }

  // epilogue: O^T/l -> aout ; lane(l31,hi) holds O[q=l31][d=db*32+8*rq+4*hi+e]
#pragma unroll
  for (int t = 0; t < 2; ++t) {
    const float inv = t == 0 ? (1.0f / lA) : (1.0f / lB);
    const int q0w = t == 0 ? q0A : q0B;
    f32x16* o = t == 0 ? oA : oB;
    u16* orow = aout + ((size_t)(q0w + l31) * B_DIM + b) * D_DIM + h * HD;
#pragma unroll
    for (int db = 0; db < 2; ++db)
#pragma unroll
      for (int rq = 0; rq < 4; ++rq) {
        u16x4 o4;
#pragma unroll
        for (int e = 0; e < 4; ++e) o4[e] = f2bf(o[db][rq * 4 + e] * inv);
        *reinterpret_cast<u16x4*>(orow + db * 32 + rq * 8 + hi * 4) = o4;
      }
  }
#undef ISSUE_K
#undef LOAD_V
#undef SCATTER_V
}

// ---------------- launch ----------------
extern "C" void kernel_launch(void* const* d_in, const int* in_sizes, int n_in,
                              void* d_out, int out_size, void* d_ws, size_t ws_size,
                              hipStream_t stream) {
  (void)in_sizes; (void)n_in; (void)out_size; (void)ws_size;
  const float* x = (const float*)d_in[0];
  const float* Wqkv = (const float*)d_in[1];
  const float* Wout = (const float*)d_in[2];
  const float* bout = (const float*)d_in[3];
  float* out = (float*)d_out;

  u16* xb = (u16*)d_ws;                               // [8192][1024]
  u16* wqkvb = xb + (size_t)MROWS * D_DIM;            // [3072][1024]
  u16* woutb = wqkvb + (size_t)QKV_N * D_DIM;         // [1024][1024]
  u16* qkv = woutb + (size_t)D_DIM * D_DIM;           // [8192][3072]
  u16* aout = qkv + (size_t)MROWS * QKV_N;            // [8192][1024]

  {
    const int n0 = MROWS * D_DIM;                     // x
    const int n01 = n0 + QKV_N * D_DIM;               // + W_qkv
    const int ntot = n01 + D_DIM * D_DIM;             // + W_out
    const int n4 = ntot / 4;
    cast3_f32_bf16<<<(n4 + 255) / 256, 256, 0, stream>>>(
        x, Wqkv, Wout, xb, n0, n01, n4);
  }

  gemm_bt<0><<<dim3(QKV_N / 128, MROWS / 128), 256, 0, stream>>>(
      xb, wqkvb, qkv, nullptr, nullptr, MROWS, QKV_N, D_DIM);

  attn_kernel<<<dim3(8, B_DIM * H_NUM), 256, 0, stream>>>(qkv, aout);

  gemm_bt<1><<<dim3(D_DIM / 128, MROWS / 128), 256, 0, stream>>>(
      aout, woutb, nullptr, out, bout, MROWS, D_DIM, D_DIM);
}